// Round 10
// baseline (128.662 us; speedup 1.0000x reference)
//
// Round 10: k_z_fast drops atomics via the round-6-verified linearity identity
// zbar[n]*127 = sum_k A_scaled[k][n] * (Qsum[k] - q[n][k]); k1/k_epi unchanged.
#include <hip/hip_runtime.h>
#include <hip/hip_bf16.h>

#define NB 8
#define NMAXN 128
#define PEH 64
#define NE 5
#define DSZ 64
#define NFEAT 8
#define TOTALN 1024         // NB*NMAXN
#define PCOLS 1280          // 4*E*PE

// out layout (FLOAT32 offsets): e_hat, x_hat, edge_mask, mask
#define OUT_XHAT (NB*NMAXN*NMAXN*NE)              // 655360
#define OUT_EM   (OUT_XHAT + TOTALN*NFEAT)        // 663552
#define OUT_MASK (OUT_EM + NB*NMAXN*NMAXN)        // 794624

// ws layout (float offsets), parameterized at launch:
//   big path:  [0,1310720) proj fp32 | zs bf16 | zbar | wpc | c1 | fac
//   small path: zs bf16 at 0 | zbar | wpc | c1 | fac   (1.33 MB, known-safe)

// ---------------- K1: fused proj (blocks 0..255) + misc (blocks 256..307), 320 thr
__global__ void k_fused1(const float* __restrict__ x, const float* __restrict__ qv,
                         const float* __restrict__ w_attn, const float* __restrict__ b_attn,
                         const float* __restrict__ w_node, const float* __restrict__ b_node,
                         const float* __restrict__ w_phi, const float* __restrict__ b_phi,
                         const float* __restrict__ w_ctx, const float* __restrict__ b_self,
                         float* __restrict__ ws, float* __restrict__ out,
                         int offZbar, int offWpc, int offC1, int offFac, int doProj)
{
    int blk = blockIdx.x, t = threadIdx.x;
    if (blk < 256) {                       // ---- proj: 4 rows x 1280 cols, K=64
        if (!doProj) return;
        __shared__ float xs[4 * 64];
        int r0 = blk * 4;
        if (t < 256) xs[t] = x[r0 * PEH + t];
        __syncthreads();
        float4 b4 = *(const float4*)&b_attn[4 * t];
        float4 a0 = b4, a1 = b4, a2 = b4, a3 = b4;
        const float* wp = w_attn + 4 * t;
        #pragma unroll 4
        for (int k = 0; k < 64; k++) {
            float4 w4 = *(const float4*)&wp[k * PCOLS];
            float x0 = xs[k], x1 = xs[64 + k], x2 = xs[128 + k], x3 = xs[192 + k];
            a0.x = fmaf(x0, w4.x, a0.x); a0.y = fmaf(x0, w4.y, a0.y); a0.z = fmaf(x0, w4.z, a0.z); a0.w = fmaf(x0, w4.w, a0.w);
            a1.x = fmaf(x1, w4.x, a1.x); a1.y = fmaf(x1, w4.y, a1.y); a1.z = fmaf(x1, w4.z, a1.z); a1.w = fmaf(x1, w4.w, a1.w);
            a2.x = fmaf(x2, w4.x, a2.x); a2.y = fmaf(x2, w4.y, a2.y); a2.z = fmaf(x2, w4.z, a2.z); a2.w = fmaf(x2, w4.w, a2.w);
            a3.x = fmaf(x3, w4.x, a3.x); a3.y = fmaf(x3, w4.y, a3.y); a3.z = fmaf(x3, w4.z, a3.z); a3.w = fmaf(x3, w4.w, a3.w);
        }
        float* pr = ws + r0 * PCOLS + 4 * t;
        *(float4*)&pr[0]         = a0;
        *(float4*)&pr[PCOLS]     = a1;
        *(float4*)&pr[2 * PCOLS] = a2;
        *(float4*)&pr[3 * PCOLS] = a3;
        return;
    }
    int b2 = blk - 256;
    if (b2 < 32) {                         // ---- x_hat: 8192 elems
        if (t < 256) {
            int g = b2 * 256 + t;
            int row = g >> 3, f = g & 7;
            const float* xr = x + row * PEH;
            float acc = b_node[f];
            #pragma unroll 8
            for (int k = 0; k < PEH; k++) acc = fmaf(xr[k], w_node[k * NFEAT + f], acc);
            out[OUT_XHAT + g] = acc;
        }
    } else if (b2 < 48) {                  // ---- edge_mask
        int base = (b2 - 32) * 8192;
        for (int g = base + t; g < base + 8192; g += 320) {
            int n = (g >> 7) & 127, m = g & 127;
            out[OUT_EM + g] = (n == m) ? 0.0f : 1.0f;
        }
    } else if (b2 == 48) {                 // ---- mask
        for (int g = t; g < 1024; g += 320) out[OUT_MASK + g] = 1.0f;
    } else if (b2 == 49) {                 // ---- consts
        if (t < 64) {
            float wpv = 0.f, bpv = 0.f;
            for (int i = 0; i < 64; i++) {
                float wc = w_ctx[i * 64 + t];
                wpv = fmaf(w_phi[i], wc, wpv);
                bpv = fmaf(b_phi[i], wc, bpv);
            }
            ws[offWpc + t] = wpv;
            ws[offC1 + t]  = b_self[t] + bpv;
        } else if (t < 72) {
            int b = t - 64;
            float qq = qv[b];
            float ang = 6.2831853071795864f * qq;
            float c = cosf(ang), s = sinf(ang);
            ws[offFac + b] = (2.0f - c) / s;
        }
    } else {                               // ---- blocks 50,51: zero zbar (fallback path;
        int base = (b2 - 50) * 2560;       //      big path overwrites, stream-ordered)
        for (int g = t; g < 2560; g += 320) ws[offZbar + base + g] = 0.0f;
    }
}

// ---------------- K2 (big path): z from proj. grid 320 = (b,e) x 8 m-slices of 16,
// 256 thr; thread tile 4n x 2m. Stores zs bf16 [b][m][e][n]; zbar via linearity
// (direct write, duplicate across the 8 m-slice blocks — bitwise identical).
__global__ void k_z_fast(float* __restrict__ ws, int zsF, int offZbar, int offFac)
{
    __shared__ alignas(16) float smA[64 * 128];   // 32 KB, scaled k-side, k-major
    __shared__ alignas(16) float smQ[64 * 20];    // 5 KB (16 m + 4 pad)
    __shared__ float qpart[256];
    __shared__ float Qs[64];

    int t = threadIdx.x;
    int blk = blockIdx.x;
    int ms = blk & 7, be = blk >> 3;
    int b = be / 5, e = be - 5 * b;
    float fac = ws[offFac + b];
    const float scale = 0.05590169943749474f;   // 1/sqrt(320)
    float sfac = scale * fac;

    const float* proj = ws;
    int kn = t >> 1, kkb = (t & 1) * 32;       // k-side staging: (n, 32 k's)
    int qm = t & 15, qkb = (t >> 4) * 4;       // q-side staging: (m-local, 4 k's)
    int qk = t & 63, qmq = t >> 6;             // Qsum: (col, m-quarter)

    int tx = t & 7, ty = t >> 3;
    int m0 = 2 * tx, n0 = 4 * ty;
    float acc[4][2] = {};
    float zb_acc = 0.f;                        // valid for t < 128 (n = t)

    for (int pass = 0; pass < 2; pass++) {
        __syncthreads();
        int colK = (pass ? 640 : 0)   + e * 64;
        int colQ = (pass ? 960 : 320) + e * 64;
        float sc = pass ? sfac : scale;
        const float* prK = proj + (b * NMAXN + kn) * PCOLS + colK + kkb;
        #pragma unroll
        for (int j4 = 0; j4 < 8; j4++) {
            float4 v = *(const float4*)&prK[4 * j4];
            smA[(kkb + 4*j4 + 0) * 128 + kn] = sc * v.x;
            smA[(kkb + 4*j4 + 1) * 128 + kn] = sc * v.y;
            smA[(kkb + 4*j4 + 2) * 128 + kn] = sc * v.z;
            smA[(kkb + 4*j4 + 3) * 128 + kn] = sc * v.w;
        }
        const float* prQ = proj + (b * NMAXN + ms * 16 + qm) * PCOLS + colQ + qkb;
        {
            float4 v = *(const float4*)&prQ[0];
            smQ[(qkb + 0) * 20 + qm] = v.x;
            smQ[(qkb + 1) * 20 + qm] = v.y;
            smQ[(qkb + 2) * 20 + qm] = v.z;
            smQ[(qkb + 3) * 20 + qm] = v.w;
        }
        // Qsum partials from global (coalesced across threads)
        {
            const float* qcol = proj + (b * NMAXN + qmq * 32) * PCOLS + colQ + qk;
            float s = 0.f;
            #pragma unroll 4
            for (int mm = 0; mm < 32; mm++) s += qcol[mm * PCOLS];
            qpart[t] = s;
        }
        __syncthreads();
        if (t < 64) Qs[t] = (qpart[t] + qpart[t + 64]) + (qpart[t + 128] + qpart[t + 192]);
        __syncthreads();
        // zbar via linearity (waves 0-1): n = t
        if (t < 128) {
            const float* rowq = proj + (b * NMAXN + t) * PCOLS + colQ;
            float d = 0.f;
            #pragma unroll 4
            for (int k = 0; k < 64; k++)
                d = fmaf(smA[k * 128 + t], Qs[k] - rowq[k], d);
            zb_acc += d;
        }
        // main z-GEMM
        for (int k = 0; k < 64; k++) {
            float4 a4 = *(const float4*)&smA[k * 128 + n0];
            float2 q2 = *(const float2*)&smQ[k * 20 + m0];
            float ar[4] = {a4.x, a4.y, a4.z, a4.w};
            #pragma unroll
            for (int r = 0; r < 4; r++) {
                acc[r][0] = fmaf(ar[r], q2.x, acc[r][0]);
                acc[r][1] = fmaf(ar[r], q2.y, acc[r][1]);
            }
        }
    }

    if (t < 128) ws[offZbar + (b * NE + e) * NMAXN + t] = zb_acc * (1.0f / 127.0f);

    // store zs bf16 [b][m][e][n] (packed 8B along n)
    __hip_bfloat16* zsb = (__hip_bfloat16*)(ws + zsF);
    #pragma unroll
    for (int c = 0; c < 2; c++) {
        int mg = ms * 16 + m0 + c;
        union { ushort4 u; __hip_bfloat16 h[4]; } pk;
        #pragma unroll
        for (int r = 0; r < 4; r++) pk.h[r] = __float2bfloat16(acc[r][c]);
        *(ushort4*)&zsb[((b * NMAXN + mg) * NE + e) * NMAXN + n0] = pk.u;
    }
}

// gelu tanh-approx: x * sigmoid(2u), u=sqrt(2/pi)(x+0.044715x^3)
__device__ __forceinline__ float gelu_fast(float x) {
    float x2 = x * x;
    float w  = -1.5957691216057308f * x * fmaf(0.044715f, x2, 1.0f);   // -2u
    float ew = __expf(w);
    return x * __builtin_amdgcn_rcpf(1.0f + ew);
}

// ---------------- K3: epilogue. grid 512 = (b x 64 m-pairs), 640 thr (t=e*128+n),
// 2 m's per thread (amortize consts + zbv, 2 independent gelu chains).
__global__ void k_epi(const float* __restrict__ ws, const float* __restrict__ w_self,
                      const float* __restrict__ w_out, const float* __restrict__ b_out,
                      float* __restrict__ out,
                      int zsF, int offZbar, int offWpc, int offC1)
{
    __shared__ alignas(16) float4 cwi[64];   // (w_self, wpc, c1, w_out)
    int t = threadIdx.x;
    int b = blockIdx.x >> 6, mp = blockIdx.x & 63;
    int m0 = 2 * mp;
    if (t < 64)
        cwi[t] = make_float4(w_self[t], ws[offWpc + t], ws[offC1 + t], w_out[t]);
    float zbv = ws[offZbar + b * 640 + t];   // already /127; [b][e][n], t=(e,n)
    __syncthreads();

    const __hip_bfloat16* zsb = (const __hip_bfloat16*)(ws + zsF);
    int e = t >> 7, n = t & 127;
    float zv0 = __bfloat162float(zsb[(b * NMAXN + m0) * 640 + t]);      // [b][m][e][n]
    float zv1 = __bfloat162float(zsb[(b * NMAXN + m0 + 1) * 640 + t]);
    float bo = b_out[0];
    float a0 = bo, a1 = bo;
    #pragma unroll 8
    for (int d = 0; d < 64; d++) {
        float4 c = cwi[d];
        float zc = fmaf(zbv, c.y, c.z);
        a0 = fmaf(gelu_fast(fmaf(zv0, c.x, zc)), c.w, a0);
        a1 = fmaf(gelu_fast(fmaf(zv1, c.x, zc)), c.w, a1);
    }
    int oo = n * NE + e;
    out[(b * NMAXN + m0) * 640 + oo]     = a0;
    out[(b * NMAXN + m0 + 1) * 640 + oo] = a1;
}

// ================= small-ws fallback path (round-5 proven) =================
__device__ __forceinline__ void z_store4(float acc[4][4], float* ws, float* zp,
                                         int zsF, int offZbar,
                                         int b, int e, int mq, int t)
{
    int tx = t & 7, ty = t >> 3;
    int m0 = 4 * tx, n0 = 4 * ty;
    __hip_bfloat16* zsb = (__hip_bfloat16*)(ws + zsF);
    float psum[4] = {0.f, 0.f, 0.f, 0.f};
    #pragma unroll
    for (int c = 0; c < 4; c++) {
        int mg = mq * 32 + m0 + c;
        union { ushort4 u; __hip_bfloat16 h[4]; } pk;
        #pragma unroll
        for (int r = 0; r < 4; r++) {
            pk.h[r] = __float2bfloat16(acc[r][c]);
            if (mg != n0 + r) psum[r] += acc[r][c];
        }
        *(ushort4*)&zsb[((b * NMAXN + mg) * NE + e) * NMAXN + n0] = pk.u;
    }
    #pragma unroll
    for (int r = 0; r < 4; r++) zp[(n0 + r) * 8 + tx] = psum[r];
    __syncthreads();
    if (t < 128) {
        float s = 0.f;
        #pragma unroll
        for (int xx = 0; xx < 8; xx++) s += zp[t * 8 + xx];
        atomicAdd(&ws[offZbar + (b * NE + e) * NMAXN + t], s);
    }
}

__global__ void k_z_slow(const float* __restrict__ x, const float* __restrict__ w_attn,
                         const float* __restrict__ b_attn, float* __restrict__ ws,
                         int zsF, int offZbar, int offFac)
{
    __shared__ alignas(16) float sm[8320 + 2304 + 1024];
    float* xsm = sm;
    float* smA = sm;
    float* smQ = sm + 8320;
    float* zp  = sm + 8320 + 2304;

    int t = threadIdx.x;
    int blk = blockIdx.x;
    int mq = blk & 3, be = blk >> 2;
    int b = be / 5, e = be - 5 * b;
    float fac = ws[offFac + b];
    const float scale = 0.05590169943749474f;
    float sfac = scale * fac;

    int kn   = t >> 1;
    int kkb  = (t & 1) * 32;
    int qm   = t & 31;
    int qkb  = (t >> 5) * 8;
    int mglo = mq * 32 + qm;

    int tx = t & 7, ty = t >> 3;
    int m0 = 4 * tx, n0 = 4 * ty;
    float acc[4][4] = {};

    for (int pass = 0; pass < 2; pass++) {
        __syncthreads();
        for (int i = t; i < 128 * 16; i += 256) {
            int n = i >> 4, dd = (i & 15) * 4;
            float4 xv = *(const float4*)&x[(b * NMAXN + n) * PEH + dd];
            float* dst = &xsm[n * 65 + dd];
            dst[0] = xv.x; dst[1] = xv.y; dst[2] = xv.z; dst[3] = xv.w;
        }
        __syncthreads();
        int colK = (pass ? 640 : 0)   + e * 64 + kkb;
        int colQ = (pass ? 960 : 320) + e * 64 + qkb;
        float rk[32], rq[8];
        #pragma unroll
        for (int j = 0; j < 32; j++) rk[j] = b_attn[colK + j];
        #pragma unroll
        for (int j = 0; j < 8; j++)  rq[j] = b_attn[colQ + j];
        for (int d = 0; d < 64; d++) {
            const float* wrow = w_attn + d * PCOLS;
            float xk = xsm[kn * 65 + d];
            float xq = xsm[mglo * 65 + d];
            #pragma unroll
            for (int j4 = 0; j4 < 8; j4++) {
                float4 w4 = *(const float4*)&wrow[colK + 4 * j4];
                rk[4*j4+0] = fmaf(xk, w4.x, rk[4*j4+0]);
                rk[4*j4+1] = fmaf(xk, w4.y, rk[4*j4+1]);
                rk[4*j4+2] = fmaf(xk, w4.z, rk[4*j4+2]);
                rk[4*j4+3] = fmaf(xk, w4.w, rk[4*j4+3]);
            }
            #pragma unroll
            for (int j4 = 0; j4 < 2; j4++) {
                float4 w4 = *(const float4*)&wrow[colQ + 4 * j4];
                rq[4*j4+0] = fmaf(xq, w4.x, rq[4*j4+0]);
                rq[4*j4+1] = fmaf(xq, w4.y, rq[4*j4+1]);
                rq[4*j4+2] = fmaf(xq, w4.z, rq[4*j4+2]);
                rq[4*j4+3] = fmaf(xq, w4.w, rq[4*j4+3]);
            }
        }
        __syncthreads();
        float sc = pass ? sfac : scale;
        #pragma unroll
        for (int j = 0; j < 32; j++) smA[(kkb + j) * 128 + kn] = sc * rk[j];
        #pragma unroll
        for (int j = 0; j < 8; j++)  smQ[(qkb + j) * 36 + qm] = rq[j];
        __syncthreads();
        for (int k = 0; k < 64; k++) {
            float4 a4 = *(const float4*)&smA[k * 128 + n0];
            float4 q4 = *(const float4*)&smQ[k * 36 + m0];
            float ar[4] = {a4.x, a4.y, a4.z, a4.w};
            float qr[4] = {q4.x, q4.y, q4.z, q4.w};
            #pragma unroll
            for (int r = 0; r < 4; r++)
                #pragma unroll
                for (int c = 0; c < 4; c++)
                    acc[r][c] = fmaf(ar[r], qr[c], acc[r][c]);
        }
    }
    __syncthreads();
    z_store4(acc, ws, zp, zsF, offZbar, b, e, mq, t);
}

__global__ void k_epi_slow(const float* __restrict__ ws, const float* __restrict__ w_self,
                           const float* __restrict__ w_out, const float* __restrict__ b_out,
                           float* __restrict__ out,
                           int zsF, int offZbar, int offWpc, int offC1)
{
    __shared__ alignas(16) float4 cwi[64];
    int t = threadIdx.x;
    int b = blockIdx.x >> 7, m = blockIdx.x & 127;
    if (t < 64)
        cwi[t] = make_float4(w_self[t], ws[offWpc + t], ws[offC1 + t], w_out[t]);
    float zbv = ws[offZbar + b * 640 + t] * (1.0f / 127.0f);
    __syncthreads();

    const __hip_bfloat16* zsb = (const __hip_bfloat16*)(ws + zsF);
    int e = t >> 7, n = t & 127;
    float zv = __bfloat162float(zsb[(b * NMAXN + m) * 640 + t]);
    float acc = b_out[0];
    #pragma unroll 8
    for (int d = 0; d < 64; d++) {
        float4 c = cwi[d];
        float arg = fmaf(zv, c.x, fmaf(zbv, c.y, c.z));
        acc = fmaf(gelu_fast(arg), c.w, acc);
    }
    out[(b * NMAXN + m) * 640 + n * NE + e] = acc;
}

extern "C" void kernel_launch(void* const* d_in, const int* in_sizes, int n_in,
                              void* d_out, int out_size, void* d_ws, size_t ws_size,
                              hipStream_t stream)
{
    const float* x      = (const float*)d_in[0];
    // d_in[1] = batch (int32) — full sorted graphs, unused
    const float* q      = (const float*)d_in[2];
    const float* w_attn = (const float*)d_in[3];
    const float* b_attn = (const float*)d_in[4];
    const float* w_node = (const float*)d_in[5];
    const float* b_node = (const float*)d_in[6];
    const float* w_phi  = (const float*)d_in[7];
    const float* b_phi  = (const float*)d_in[8];
    const float* w_ctx  = (const float*)d_in[9];
    const float* w_self = (const float*)d_in[10];
    const float* b_self = (const float*)d_in[11];
    const float* w_out  = (const float*)d_in[12];
    const float* b_out  = (const float*)d_in[13];
    float* ws  = (float*)d_ws;
    float* out = (float*)d_out;

    // ws_size is fixed per environment -> branch is deterministic across calls.
    const bool big = ws_size >= (size_t)(1643656 * 4 + 64);
    const int zsF     = big ? (TOTALN * PCOLS) : 0;   // zs (bf16) start, float units
    const int offZbar = zsF + 327680;
    const int offWpc  = offZbar + 5120;
    const int offC1   = offWpc + 64;
    const int offFac  = offC1 + 64;

    k_fused1<<<308, 320, 0, stream>>>(x, q, w_attn, b_attn, w_node, b_node,
                                      w_phi, b_phi, w_ctx, b_self,
                                      ws, out, offZbar, offWpc, offC1, offFac, big ? 1 : 0);
    if (big) {
        k_z_fast<<<320, 256, 0, stream>>>(ws, zsF, offZbar, offFac);
        k_epi<<<512, 640, 0, stream>>>(ws, w_self, w_out, b_out, out,
                                       zsF, offZbar, offWpc, offC1);
    } else {
        k_z_slow<<<160, 256, 0, stream>>>(x, w_attn, b_attn, ws, zsF, offZbar, offFac);
        k_epi_slow<<<1024, 640, 0, stream>>>(ws, w_self, w_out, b_out, out,
                                             zsF, offZbar, offWpc, offC1);
    }
}

// Round 11
// 119.098 us; speedup vs baseline: 1.0803x; 1.0803x over previous
//
// Round 11 = revert to round-9 verbatim (measured best, 119.5 µs).
// Round-10's linearity-zbar variant regressed (+9 µs): 8x redundant Qsum/zbar
// work per (b,e) + uncoalesced rowq reads + extra barriers — atomics were cheaper.
#include <hip/hip_runtime.h>
#include <hip/hip_bf16.h>

#define NB 8
#define NMAXN 128
#define PEH 64
#define NE 5
#define DSZ 64
#define NFEAT 8
#define TOTALN 1024         // NB*NMAXN
#define PCOLS 1280          // 4*E*PE

// out layout (FLOAT32 offsets): e_hat, x_hat, edge_mask, mask
#define OUT_XHAT (NB*NMAXN*NMAXN*NE)              // 655360
#define OUT_EM   (OUT_XHAT + TOTALN*NFEAT)        // 663552
#define OUT_MASK (OUT_EM + NB*NMAXN*NMAXN)        // 794624

// ws layout (float offsets), parameterized at launch:
//   big path:  [0,1310720) proj fp32 | zs bf16 | zbar | wpc | c1 | fac
//   small path: zs bf16 at 0 | zbar | wpc | c1 | fac   (1.33 MB, known-safe)

// ---------------- K1: fused proj (blocks 0..255) + misc (blocks 256..307), 320 thr
__global__ void k_fused1(const float* __restrict__ x, const float* __restrict__ qv,
                         const float* __restrict__ w_attn, const float* __restrict__ b_attn,
                         const float* __restrict__ w_node, const float* __restrict__ b_node,
                         const float* __restrict__ w_phi, const float* __restrict__ b_phi,
                         const float* __restrict__ w_ctx, const float* __restrict__ b_self,
                         float* __restrict__ ws, float* __restrict__ out,
                         int offZbar, int offWpc, int offC1, int offFac, int doProj)
{
    int blk = blockIdx.x, t = threadIdx.x;
    if (blk < 256) {                       // ---- proj: 4 rows x 1280 cols, K=64
        if (!doProj) return;
        __shared__ float xs[4 * 64];
        int r0 = blk * 4;
        if (t < 256) xs[t] = x[r0 * PEH + t];
        __syncthreads();
        float4 b4 = *(const float4*)&b_attn[4 * t];
        float4 a0 = b4, a1 = b4, a2 = b4, a3 = b4;
        const float* wp = w_attn + 4 * t;
        #pragma unroll 4
        for (int k = 0; k < 64; k++) {
            float4 w4 = *(const float4*)&wp[k * PCOLS];
            float x0 = xs[k], x1 = xs[64 + k], x2 = xs[128 + k], x3 = xs[192 + k];
            a0.x = fmaf(x0, w4.x, a0.x); a0.y = fmaf(x0, w4.y, a0.y); a0.z = fmaf(x0, w4.z, a0.z); a0.w = fmaf(x0, w4.w, a0.w);
            a1.x = fmaf(x1, w4.x, a1.x); a1.y = fmaf(x1, w4.y, a1.y); a1.z = fmaf(x1, w4.z, a1.z); a1.w = fmaf(x1, w4.w, a1.w);
            a2.x = fmaf(x2, w4.x, a2.x); a2.y = fmaf(x2, w4.y, a2.y); a2.z = fmaf(x2, w4.z, a2.z); a2.w = fmaf(x2, w4.w, a2.w);
            a3.x = fmaf(x3, w4.x, a3.x); a3.y = fmaf(x3, w4.y, a3.y); a3.z = fmaf(x3, w4.z, a3.z); a3.w = fmaf(x3, w4.w, a3.w);
        }
        float* pr = ws + r0 * PCOLS + 4 * t;
        *(float4*)&pr[0]         = a0;
        *(float4*)&pr[PCOLS]     = a1;
        *(float4*)&pr[2 * PCOLS] = a2;
        *(float4*)&pr[3 * PCOLS] = a3;
        return;
    }
    int b2 = blk - 256;
    if (b2 < 32) {                         // ---- x_hat: 8192 elems
        if (t < 256) {
            int g = b2 * 256 + t;
            int row = g >> 3, f = g & 7;
            const float* xr = x + row * PEH;
            float acc = b_node[f];
            #pragma unroll 8
            for (int k = 0; k < PEH; k++) acc = fmaf(xr[k], w_node[k * NFEAT + f], acc);
            out[OUT_XHAT + g] = acc;
        }
    } else if (b2 < 48) {                  // ---- edge_mask
        int base = (b2 - 32) * 8192;
        for (int g = base + t; g < base + 8192; g += 320) {
            int n = (g >> 7) & 127, m = g & 127;
            out[OUT_EM + g] = (n == m) ? 0.0f : 1.0f;
        }
    } else if (b2 == 48) {                 // ---- mask
        for (int g = t; g < 1024; g += 320) out[OUT_MASK + g] = 1.0f;
    } else if (b2 == 49) {                 // ---- consts
        if (t < 64) {
            float wpv = 0.f, bpv = 0.f;
            for (int i = 0; i < 64; i++) {
                float wc = w_ctx[i * 64 + t];
                wpv = fmaf(w_phi[i], wc, wpv);
                bpv = fmaf(b_phi[i], wc, bpv);
            }
            ws[offWpc + t] = wpv;
            ws[offC1 + t]  = b_self[t] + bpv;
        } else if (t < 72) {
            int b = t - 64;
            float qq = qv[b];
            float ang = 6.2831853071795864f * qq;
            float c = cosf(ang), s = sinf(ang);
            ws[offFac + b] = (2.0f - c) / s;
        }
    } else {                               // ---- blocks 50,51: zero zbar
        int base = (b2 - 50) * 2560;
        for (int g = t; g < 2560; g += 320) ws[offZbar + base + g] = 0.0f;
    }
}

// ---------------- K2 (big path): z from proj. grid 320 = (b,e) x 8 m-slices of 16,
// 256 thr; thread tile 4n x 2m. Stores zs bf16 [b][m][e][n] + zbar atomics.
__global__ void k_z_fast(float* __restrict__ ws, int zsF, int offZbar, int offFac)
{
    __shared__ alignas(16) float sm[8192 + 1280 + 1024];   // 42 KB
    float* smA = sm;               // [64][128] k-major
    float* smQ = sm + 8192;        // [64][20]  (16 m + 4 pad)
    float* zp  = sm + 8192 + 1280; // [128][8]

    int t = threadIdx.x;
    int blk = blockIdx.x;
    int ms = blk & 7, be = blk >> 3;
    int b = be / 5, e = be - 5 * b;
    float fac = ws[offFac + b];
    const float scale = 0.05590169943749474f;   // 1/sqrt(320)
    float sfac = scale * fac;

    const float* proj = ws;
    int kn = t >> 1, kkb = (t & 1) * 32;       // k-side: (n, 32 k's)
    int qm = t & 15, qkb = (t >> 4) * 4;       // q-side: (m-local, 4 k's)

    int tx = t & 7, ty = t >> 3;
    int m0 = 2 * tx, n0 = 4 * ty;
    float acc[4][2] = {};

    for (int pass = 0; pass < 2; pass++) {
        __syncthreads();
        int colK = (pass ? 640 : 0)   + e * 64;
        int colQ = (pass ? 960 : 320) + e * 64;
        float sc = pass ? sfac : scale;
        const float* prK = proj + (b * NMAXN + kn) * PCOLS + colK + kkb;
        #pragma unroll
        for (int j4 = 0; j4 < 8; j4++) {
            float4 v = *(const float4*)&prK[4 * j4];
            smA[(kkb + 4*j4 + 0) * 128 + kn] = sc * v.x;
            smA[(kkb + 4*j4 + 1) * 128 + kn] = sc * v.y;
            smA[(kkb + 4*j4 + 2) * 128 + kn] = sc * v.z;
            smA[(kkb + 4*j4 + 3) * 128 + kn] = sc * v.w;
        }
        const float* prQ = proj + (b * NMAXN + ms * 16 + qm) * PCOLS + colQ + qkb;
        {
            float4 v = *(const float4*)&prQ[0];
            smQ[(qkb + 0) * 20 + qm] = v.x;
            smQ[(qkb + 1) * 20 + qm] = v.y;
            smQ[(qkb + 2) * 20 + qm] = v.z;
            smQ[(qkb + 3) * 20 + qm] = v.w;
        }
        __syncthreads();
        for (int k = 0; k < 64; k++) {
            float4 a4 = *(const float4*)&smA[k * 128 + n0];
            float2 q2 = *(const float2*)&smQ[k * 20 + m0];
            float ar[4] = {a4.x, a4.y, a4.z, a4.w};
            #pragma unroll
            for (int r = 0; r < 4; r++) {
                acc[r][0] = fmaf(ar[r], q2.x, acc[r][0]);
                acc[r][1] = fmaf(ar[r], q2.y, acc[r][1]);
            }
        }
    }
    __syncthreads();

    // store zs bf16 [b][m][e][n] (packed 8B along n) + zbar partials
    __hip_bfloat16* zsb = (__hip_bfloat16*)(ws + zsF);
    float psum[4] = {0.f, 0.f, 0.f, 0.f};
    #pragma unroll
    for (int c = 0; c < 2; c++) {
        int mg = ms * 16 + m0 + c;
        union { ushort4 u; __hip_bfloat16 h[4]; } pk;
        #pragma unroll
        for (int r = 0; r < 4; r++) {
            pk.h[r] = __float2bfloat16(acc[r][c]);
            if (mg != n0 + r) psum[r] += acc[r][c];
        }
        *(ushort4*)&zsb[((b * NMAXN + mg) * NE + e) * NMAXN + n0] = pk.u;
    }
    #pragma unroll
    for (int r = 0; r < 4; r++) zp[(n0 + r) * 8 + tx] = psum[r];
    __syncthreads();
    if (t < 128) {
        float s = 0.f;
        #pragma unroll
        for (int xx = 0; xx < 8; xx++) s += zp[t * 8 + xx];
        atomicAdd(&ws[offZbar + (b * NE + e) * NMAXN + t], s);
    }
}

// gelu tanh-approx: x * sigmoid(2u), u=sqrt(2/pi)(x+0.044715x^3)
__device__ __forceinline__ float gelu_fast(float x) {
    float x2 = x * x;
    float w  = -1.5957691216057308f * x * fmaf(0.044715f, x2, 1.0f);   // -2u
    float ew = __expf(w);
    return x * __builtin_amdgcn_rcpf(1.0f + ew);
}

// ---------------- K3: epilogue. grid 512 = (b x 64 m-pairs), 640 thr (t=e*128+n),
// 2 m's per thread (amortize consts + zbv, 2 independent gelu chains).
__global__ void k_epi(const float* __restrict__ ws, const float* __restrict__ w_self,
                      const float* __restrict__ w_out, const float* __restrict__ b_out,
                      float* __restrict__ out,
                      int zsF, int offZbar, int offWpc, int offC1)
{
    __shared__ alignas(16) float4 cwi[64];   // (w_self, wpc, c1, w_out)
    int t = threadIdx.x;
    int b = blockIdx.x >> 6, mp = blockIdx.x & 63;
    int m0 = 2 * mp;
    if (t < 64)
        cwi[t] = make_float4(w_self[t], ws[offWpc + t], ws[offC1 + t], w_out[t]);
    float zbv = ws[offZbar + b * 640 + t] * (1.0f / 127.0f);   // [b][e][n], t=(e,n)
    __syncthreads();

    const __hip_bfloat16* zsb = (const __hip_bfloat16*)(ws + zsF);
    int e = t >> 7, n = t & 127;
    float zv0 = __bfloat162float(zsb[(b * NMAXN + m0) * 640 + t]);      // [b][m][e][n]
    float zv1 = __bfloat162float(zsb[(b * NMAXN + m0 + 1) * 640 + t]);
    float bo = b_out[0];
    float a0 = bo, a1 = bo;
    #pragma unroll 8
    for (int d = 0; d < 64; d++) {
        float4 c = cwi[d];
        float zc = fmaf(zbv, c.y, c.z);
        a0 = fmaf(gelu_fast(fmaf(zv0, c.x, zc)), c.w, a0);
        a1 = fmaf(gelu_fast(fmaf(zv1, c.x, zc)), c.w, a1);
    }
    int oo = n * NE + e;
    out[(b * NMAXN + m0) * 640 + oo]     = a0;
    out[(b * NMAXN + m0 + 1) * 640 + oo] = a1;
}

// ================= small-ws fallback path (round-5 proven) =================
__device__ __forceinline__ void z_store4(float acc[4][4], float* ws, float* zp,
                                         int zsF, int offZbar,
                                         int b, int e, int mq, int t)
{
    int tx = t & 7, ty = t >> 3;
    int m0 = 4 * tx, n0 = 4 * ty;
    __hip_bfloat16* zsb = (__hip_bfloat16*)(ws + zsF);
    float psum[4] = {0.f, 0.f, 0.f, 0.f};
    #pragma unroll
    for (int c = 0; c < 4; c++) {
        int mg = mq * 32 + m0 + c;
        union { ushort4 u; __hip_bfloat16 h[4]; } pk;
        #pragma unroll
        for (int r = 0; r < 4; r++) {
            pk.h[r] = __float2bfloat16(acc[r][c]);
            if (mg != n0 + r) psum[r] += acc[r][c];
        }
        *(ushort4*)&zsb[((b * NMAXN + mg) * NE + e) * NMAXN + n0] = pk.u;
    }
    #pragma unroll
    for (int r = 0; r < 4; r++) zp[(n0 + r) * 8 + tx] = psum[r];
    __syncthreads();
    if (t < 128) {
        float s = 0.f;
        #pragma unroll
        for (int xx = 0; xx < 8; xx++) s += zp[t * 8 + xx];
        atomicAdd(&ws[offZbar + (b * NE + e) * NMAXN + t], s);
    }
}

__global__ void k_z_slow(const float* __restrict__ x, const float* __restrict__ w_attn,
                         const float* __restrict__ b_attn, float* __restrict__ ws,
                         int zsF, int offZbar, int offFac)
{
    __shared__ alignas(16) float sm[8320 + 2304 + 1024];
    float* xsm = sm;
    float* smA = sm;
    float* smQ = sm + 8320;
    float* zp  = sm + 8320 + 2304;

    int t = threadIdx.x;
    int blk = blockIdx.x;
    int mq = blk & 3, be = blk >> 2;
    int b = be / 5, e = be - 5 * b;
    float fac = ws[offFac + b];
    const float scale = 0.05590169943749474f;
    float sfac = scale * fac;

    int kn   = t >> 1;
    int kkb  = (t & 1) * 32;
    int qm   = t & 31;
    int qkb  = (t >> 5) * 8;
    int mglo = mq * 32 + qm;

    int tx = t & 7, ty = t >> 3;
    int m0 = 4 * tx, n0 = 4 * ty;
    float acc[4][4] = {};

    for (int pass = 0; pass < 2; pass++) {
        __syncthreads();
        for (int i = t; i < 128 * 16; i += 256) {
            int n = i >> 4, dd = (i & 15) * 4;
            float4 xv = *(const float4*)&x[(b * NMAXN + n) * PEH + dd];
            float* dst = &xsm[n * 65 + dd];
            dst[0] = xv.x; dst[1] = xv.y; dst[2] = xv.z; dst[3] = xv.w;
        }
        __syncthreads();
        int colK = (pass ? 640 : 0)   + e * 64 + kkb;
        int colQ = (pass ? 960 : 320) + e * 64 + qkb;
        float rk[32], rq[8];
        #pragma unroll
        for (int j = 0; j < 32; j++) rk[j] = b_attn[colK + j];
        #pragma unroll
        for (int j = 0; j < 8; j++)  rq[j] = b_attn[colQ + j];
        for (int d = 0; d < 64; d++) {
            const float* wrow = w_attn + d * PCOLS;
            float xk = xsm[kn * 65 + d];
            float xq = xsm[mglo * 65 + d];
            #pragma unroll
            for (int j4 = 0; j4 < 8; j4++) {
                float4 w4 = *(const float4*)&wrow[colK + 4 * j4];
                rk[4*j4+0] = fmaf(xk, w4.x, rk[4*j4+0]);
                rk[4*j4+1] = fmaf(xk, w4.y, rk[4*j4+1]);
                rk[4*j4+2] = fmaf(xk, w4.z, rk[4*j4+2]);
                rk[4*j4+3] = fmaf(xk, w4.w, rk[4*j4+3]);
            }
            #pragma unroll
            for (int j4 = 0; j4 < 2; j4++) {
                float4 w4 = *(const float4*)&wrow[colQ + 4 * j4];
                rq[4*j4+0] = fmaf(xq, w4.x, rq[4*j4+0]);
                rq[4*j4+1] = fmaf(xq, w4.y, rq[4*j4+1]);
                rq[4*j4+2] = fmaf(xq, w4.z, rq[4*j4+2]);
                rq[4*j4+3] = fmaf(xq, w4.w, rq[4*j4+3]);
            }
        }
        __syncthreads();
        float sc = pass ? sfac : scale;
        #pragma unroll
        for (int j = 0; j < 32; j++) smA[(kkb + j) * 128 + kn] = sc * rk[j];
        #pragma unroll
        for (int j = 0; j < 8; j++)  smQ[(qkb + j) * 36 + qm] = rq[j];
        __syncthreads();
        for (int k = 0; k < 64; k++) {
            float4 a4 = *(const float4*)&smA[k * 128 + n0];
            float4 q4 = *(const float4*)&smQ[k * 36 + m0];
            float ar[4] = {a4.x, a4.y, a4.z, a4.w};
            float qr[4] = {q4.x, q4.y, q4.z, q4.w};
            #pragma unroll
            for (int r = 0; r < 4; r++)
                #pragma unroll
                for (int c = 0; c < 4; c++)
                    acc[r][c] = fmaf(ar[r], qr[c], acc[r][c]);
        }
    }
    __syncthreads();
    z_store4(acc, ws, zp, zsF, offZbar, b, e, mq, t);
}

__global__ void k_epi_slow(const float* __restrict__ ws, const float* __restrict__ w_self,
                           const float* __restrict__ w_out, const float* __restrict__ b_out,
                           float* __restrict__ out,
                           int zsF, int offZbar, int offWpc, int offC1)
{
    __shared__ alignas(16) float4 cwi[64];
    int t = threadIdx.x;
    int b = blockIdx.x >> 7, m = blockIdx.x & 127;
    if (t < 64)
        cwi[t] = make_float4(w_self[t], ws[offWpc + t], ws[offC1 + t], w_out[t]);
    float zbv = ws[offZbar + b * 640 + t] * (1.0f / 127.0f);
    __syncthreads();

    const __hip_bfloat16* zsb = (const __hip_bfloat16*)(ws + zsF);
    int e = t >> 7, n = t & 127;
    float zv = __bfloat162float(zsb[(b * NMAXN + m) * 640 + t]);
    float acc = b_out[0];
    #pragma unroll 8
    for (int d = 0; d < 64; d++) {
        float4 c = cwi[d];
        float arg = fmaf(zv, c.x, fmaf(zbv, c.y, c.z));
        acc = fmaf(gelu_fast(arg), c.w, acc);
    }
    out[(b * NMAXN + m) * 640 + n * NE + e] = acc;
}

extern "C" void kernel_launch(void* const* d_in, const int* in_sizes, int n_in,
                              void* d_out, int out_size, void* d_ws, size_t ws_size,
                              hipStream_t stream)
{
    const float* x      = (const float*)d_in[0];
    // d_in[1] = batch (int32) — full sorted graphs, unused
    const float* q      = (const float*)d_in[2];
    const float* w_attn = (const float*)d_in[3];
    const float* b_attn = (const float*)d_in[4];
    const float* w_node = (const float*)d_in[5];
    const float* b_node = (const float*)d_in[6];
    const float* w_phi  = (const float*)d_in[7];
    const float* b_phi  = (const float*)d_in[8];
    const float* w_ctx  = (const float*)d_in[9];
    const float* w_self = (const float*)d_in[10];
    const float* b_self = (const float*)d_in[11];
    const float* w_out  = (const float*)d_in[12];
    const float* b_out  = (const float*)d_in[13];
    float* ws  = (float*)d_ws;
    float* out = (float*)d_out;

    // ws_size is fixed per environment -> branch is deterministic across calls.
    const bool big = ws_size >= (size_t)(1643656 * 4 + 64);
    const int zsF     = big ? (TOTALN * PCOLS) : 0;   // zs (bf16) start, float units
    const int offZbar = zsF + 327680;
    const int offWpc  = offZbar + 5120;
    const int offC1   = offWpc + 64;
    const int offFac  = offC1 + 64;

    k_fused1<<<308, 320, 0, stream>>>(x, q, w_attn, b_attn, w_node, b_node,
                                      w_phi, b_phi, w_ctx, b_self,
                                      ws, out, offZbar, offWpc, offC1, offFac, big ? 1 : 0);
    if (big) {
        k_z_fast<<<320, 256, 0, stream>>>(ws, zsF, offZbar, offFac);
        k_epi<<<512, 640, 0, stream>>>(ws, w_self, w_out, b_out, out,
                                       zsF, offZbar, offWpc, offC1);
    } else {
        k_z_slow<<<160, 256, 0, stream>>>(x, w_attn, b_attn, ws, zsF, offZbar, offFac);
        k_epi_slow<<<1024, 640, 0, stream>>>(ws, w_self, w_out, b_out, out,
                                             zsF, offZbar, offWpc, offC1);
    }
}